// Round 1
// baseline (1170.913 us; speedup 1.0000x reference)
//
#include <hip/hip_runtime.h>

#define MAXDEG 96

// ---------------------------------------------------------------------------
// Build padded adjacency buckets: for each edge (src,dst), append src to
// dst's bucket. deg[] counts true in-degree (matches reference cnt).
// ---------------------------------------------------------------------------
__global__ __launch_bounds__(256) void build_buckets(
    const int* __restrict__ src, const int* __restrict__ dst,
    int* __restrict__ deg, int* __restrict__ col, int E)
{
    int e = blockIdx.x * 256 + threadIdx.x;
    if (e >= E) return;
    int d = dst[e];
    int slot = atomicAdd(&deg[d], 1);
    if (slot < MAXDEG) col[(size_t)d * MAXDEG + slot] = src[e];
}

// ---------------------------------------------------------------------------
// Mean-aggregate neighbor rows: out[n][c] = (sum_{s in nbr(n)} X[s][c]) / max(deg,1)
// One block per node, one thread per channel.
// ---------------------------------------------------------------------------
template<int C>
__global__ __launch_bounds__(C) void agg_mean(
    const float* __restrict__ X, const int* __restrict__ col,
    const int* __restrict__ deg, float* __restrict__ out)
{
    int n = blockIdx.x;
    int c = threadIdx.x;
    int d = deg[n];
    int dc = d < MAXDEG ? d : MAXDEG;
    const int* cl = col + (size_t)n * MAXDEG;
    float acc = 0.f;
    for (int i = 0; i < dc; ++i) {
        int s = cl[i];
        acc += X[(size_t)s * C + c];
    }
    float denom = (float)(d > 1 ? d : 1);
    out[(size_t)n * C + c] = acc / denom;
}

// ---------------------------------------------------------------------------
// Dual GEMM: C = act(A1@W1 [+ A2@W2] + bias).  A row-major [M][K], W [K][N].
// 64x64 tile, BK=16, 256 threads, 4x4 accum per thread. f32 (no fp32 MFMA).
// ---------------------------------------------------------------------------
__global__ __launch_bounds__(256) void gemm_dual(
    const float* __restrict__ A1, const float* __restrict__ W1,
    const float* __restrict__ A2, const float* __restrict__ W2,
    const float* __restrict__ bias, float* __restrict__ Cout,
    int M, int N, int K, int relu)
{
    __shared__ float As[16][64];
    __shared__ float Ws[16][64];
    const int m0 = blockIdx.x * 64;
    const int n0 = blockIdx.y * 64;
    const int t  = threadIdx.x;
    const int tn = t & 15;    // n-group: consecutive threads -> consecutive n (coalesced stores)
    const int tm = t >> 4;    // m-group

    float acc[4][4] = {};

    for (int phase = 0; phase < 2; ++phase) {
        const float* A = phase ? A2 : A1;
        const float* W = phase ? W2 : W1;
        if (A == nullptr) break;
        for (int k0 = 0; k0 < K; k0 += 16) {
            // A tile: rows m0..m0+63, cols k0..k0+15 -> As[k][m] (transposed)
            {
                int r  = t >> 2;          // 0..63
                int kk = (t & 3) * 4;     // 0,4,8,12
                float4 v = make_float4(0.f, 0.f, 0.f, 0.f);
                int rg = m0 + r;
                if (rg < M) v = *(const float4*)&A[(size_t)rg * K + k0 + kk];
                As[kk + 0][r] = v.x;
                As[kk + 1][r] = v.y;
                As[kk + 2][r] = v.z;
                As[kk + 3][r] = v.w;
            }
            // W tile: rows k0..k0+15, cols n0..n0+63 -> Ws[k][n]
            {
                int kk = t >> 4;          // 0..15
                int nn = (t & 15) * 4;    // 0..60
                *(float4*)&Ws[kk][nn] = *(const float4*)&W[(size_t)(k0 + kk) * N + n0 + nn];
            }
            __syncthreads();
            #pragma unroll
            for (int k = 0; k < 16; ++k) {
                float4 a = *(const float4*)&As[k][tm * 4];
                float4 w = *(const float4*)&Ws[k][tn * 4];
                acc[0][0] += a.x * w.x; acc[0][1] += a.x * w.y; acc[0][2] += a.x * w.z; acc[0][3] += a.x * w.w;
                acc[1][0] += a.y * w.x; acc[1][1] += a.y * w.y; acc[1][2] += a.y * w.z; acc[1][3] += a.y * w.w;
                acc[2][0] += a.z * w.x; acc[2][1] += a.z * w.y; acc[2][2] += a.z * w.z; acc[2][3] += a.z * w.w;
                acc[3][0] += a.w * w.x; acc[3][1] += a.w * w.y; acc[3][2] += a.w * w.z; acc[3][3] += a.w * w.w;
            }
            __syncthreads();
        }
    }

    float4 b4 = *(const float4*)&bias[n0 + tn * 4];
    #pragma unroll
    for (int i = 0; i < 4; ++i) {
        int m = m0 + tm * 4 + i;
        if (m >= M) break;
        float4 v;
        v.x = acc[i][0] + b4.x;
        v.y = acc[i][1] + b4.y;
        v.z = acc[i][2] + b4.z;
        v.w = acc[i][3] + b4.w;
        if (relu) {
            v.x = fmaxf(v.x, 0.f); v.y = fmaxf(v.y, 0.f);
            v.z = fmaxf(v.z, 0.f); v.w = fmaxf(v.w, 0.f);
        }
        *(float4*)&Cout[(size_t)m * N + n0 + tn * 4] = v;
    }
}

// ---------------------------------------------------------------------------
// logits = hid @ Wc2 + bc2   (K=256, 2 outputs). One thread per node.
// ---------------------------------------------------------------------------
__global__ __launch_bounds__(256) void logits_kernel(
    const float* __restrict__ hid, const float* __restrict__ Wc2,
    const float* __restrict__ bc2, float* __restrict__ out, int M)
{
    __shared__ float w0[256], w1[256];
    int t = threadIdx.x;
    w0[t] = Wc2[t * 2 + 0];
    w1[t] = Wc2[t * 2 + 1];
    __syncthreads();
    int n = blockIdx.x * 256 + t;
    if (n >= M) return;
    const float* row = hid + (size_t)n * 256;
    float a0 = bc2[0], a1 = bc2[1];
    for (int k = 0; k < 256; k += 4) {
        float4 v = *(const float4*)&row[k];
        a0 += v.x * w0[k] + v.y * w0[k + 1] + v.z * w0[k + 2] + v.w * w0[k + 3];
        a1 += v.x * w1[k] + v.y * w1[k + 1] + v.z * w1[k + 2] + v.w * w1[k + 3];
    }
    out[(size_t)n * 2 + 0] = a0;
    out[(size_t)n * 2 + 1] = a1;
}

// ---------------------------------------------------------------------------
extern "C" void kernel_launch(void* const* d_in, const int* in_sizes, int n_in,
                              void* d_out, int out_size, void* d_ws, size_t ws_size,
                              hipStream_t stream)
{
    const float* x   = (const float*)d_in[0];
    const int*   ei  = (const int*)d_in[1];
    const float* Wl1 = (const float*)d_in[2];
    const float* Wr1 = (const float*)d_in[3];
    const float* b1  = (const float*)d_in[4];
    const float* Wl2 = (const float*)d_in[5];
    const float* Wr2 = (const float*)d_in[6];
    const float* b2  = (const float*)d_in[7];
    const float* Wc1 = (const float*)d_in[8];
    const float* bc1 = (const float*)d_in[9];
    const float* Wc2 = (const float*)d_in[10];
    const float* bc2 = (const float*)d_in[11];

    const int N = in_sizes[0] / 128;   // 100000
    const int E = in_sizes[1] / 2;     // 1600000

    char* ws = (char*)d_ws;
    size_t off = 0;
    auto alloc = [&](size_t bytes) -> void* {
        void* p = ws + off;
        off += (bytes + 255) & ~(size_t)255;
        return p;
    };
    int*   deg   = (int*)  alloc((size_t)N * 4);
    int*   col   = (int*)  alloc((size_t)N * MAXDEG * 4);
    float* meanb = (float*)alloc((size_t)N * 256 * 4);  // mean1 [N][128] / mean2 [N][256] / hid [N][256]
    float* h1    = (float*)alloc((size_t)N * 256 * 4);

    float* h2     = (float*)d_out;                       // [N][128]  (output 0)
    float* logits = (float*)d_out + (size_t)N * 128;     // [N][2]    (output 1)

    hipMemsetAsync(deg, 0, (size_t)N * 4, stream);
    build_buckets<<<dim3((E + 255) / 256), dim3(256), 0, stream>>>(ei, ei + E, deg, col, E);

    // Layer 1: h1 = relu(mean(x) @ Wl1 + x @ Wr1 + b1)   [N][256]
    agg_mean<128><<<dim3(N), dim3(128), 0, stream>>>(x, col, deg, meanb);
    gemm_dual<<<dim3((N + 63) / 64, 256 / 64), dim3(256), 0, stream>>>(
        meanb, Wl1, x, Wr1, b1, h1, N, 256, 128, 1);

    // Layer 2: h2 = mean(h1) @ Wl2 + h1 @ Wr2 + b2       [N][128] -> d_out
    agg_mean<256><<<dim3(N), dim3(256), 0, stream>>>(h1, col, deg, meanb);
    gemm_dual<<<dim3((N + 63) / 64, 128 / 64), dim3(256), 0, stream>>>(
        meanb, Wl2, h1, Wr2, b2, h2, N, 128, 256, 0);

    // Classifier: hid = relu(h2 @ Wc1 + bc1) [N][256] (reuse meanb), then logits
    gemm_dual<<<dim3((N + 63) / 64, 256 / 64), dim3(256), 0, stream>>>(
        h2, Wc1, nullptr, nullptr, bc1, meanb, N, 256, 128, 1);
    logits_kernel<<<dim3((N + 255) / 256), dim3(256), 0, stream>>>(
        meanb, Wc2, bc2, logits, N);
}

// Round 2
// 841.087 us; speedup vs baseline: 1.3921x; 1.3921x over previous
//
#include <hip/hip_runtime.h>

#define MAXDEG 96

// ---------------------------------------------------------------------------
// Build padded adjacency buckets: for each edge (src,dst), append src to
// dst's bucket. deg[] counts true in-degree (matches reference cnt).
// ---------------------------------------------------------------------------
__global__ __launch_bounds__(256) void build_buckets(
    const int* __restrict__ src, const int* __restrict__ dst,
    int* __restrict__ deg, int* __restrict__ col, int E)
{
    int e = blockIdx.x * 256 + threadIdx.x;
    if (e >= E) return;
    int d = dst[e];
    int slot = atomicAdd(&deg[d], 1);
    if (slot < MAXDEG) col[(size_t)d * MAXDEG + slot] = src[e];
}

// ---------------------------------------------------------------------------
// Mean-aggregate v2: one wave per node, V floats per lane, edge loop
// unrolled x4 with int4 index preload -> 4 independent row-gathers in flight.
// ---------------------------------------------------------------------------
template<int C>
__global__ __launch_bounds__(256) void agg_mean2(
    const float* __restrict__ X, const int* __restrict__ col,
    const int* __restrict__ deg, float* __restrict__ out, int N)
{
    constexpr int V = C / 64;   // floats per lane (2 or 4)
    int gw = (blockIdx.x * 256 + threadIdx.x) >> 6;
    if (gw >= N) return;
    int lane = threadIdx.x & 63;
    int d = deg[gw];
    int dc = d < MAXDEG ? d : MAXDEG;
    const int* cl = col + (size_t)gw * MAXDEG;
    float acc[V] = {};
    int i = 0;
    for (; i + 4 <= dc; i += 4) {
        int4 id4 = *(const int4*)(cl + i);
        const float* p0 = X + (size_t)id4.x * C + lane * V;
        const float* p1 = X + (size_t)id4.y * C + lane * V;
        const float* p2 = X + (size_t)id4.z * C + lane * V;
        const float* p3 = X + (size_t)id4.w * C + lane * V;
        if constexpr (V == 2) {
            float2 v0 = *(const float2*)p0, v1 = *(const float2*)p1;
            float2 v2 = *(const float2*)p2, v3 = *(const float2*)p3;
            acc[0] += (v0.x + v1.x) + (v2.x + v3.x);
            acc[1] += (v0.y + v1.y) + (v2.y + v3.y);
        } else {
            float4 v0 = *(const float4*)p0, v1 = *(const float4*)p1;
            float4 v2 = *(const float4*)p2, v3 = *(const float4*)p3;
            acc[0] += (v0.x + v1.x) + (v2.x + v3.x);
            acc[1] += (v0.y + v1.y) + (v2.y + v3.y);
            acc[2] += (v0.z + v1.z) + (v2.z + v3.z);
            acc[3] += (v0.w + v1.w) + (v2.w + v3.w);
        }
    }
    for (; i < dc; ++i) {
        const float* p = X + (size_t)cl[i] * C + lane * V;
        if constexpr (V == 2) {
            float2 v = *(const float2*)p;
            acc[0] += v.x; acc[1] += v.y;
        } else {
            float4 v = *(const float4*)p;
            acc[0] += v.x; acc[1] += v.y; acc[2] += v.z; acc[3] += v.w;
        }
    }
    float inv = 1.0f / (float)(d > 1 ? d : 1);
    float* o = out + (size_t)gw * C + lane * V;
    if constexpr (V == 2) {
        *(float2*)o = make_float2(acc[0] * inv, acc[1] * inv);
    } else {
        *(float4*)o = make_float4(acc[0] * inv, acc[1] * inv, acc[2] * inv, acc[3] * inv);
    }
}

// ---------------------------------------------------------------------------
// GEMM v2: C = act(A1@W1 [+ A2@W2] [+ addbuf] [+ bias]).
// 128x128 tile, BK=16, 256 threads, 8x8 microtile (lo/hi 4+4 split so LDS
// reads are <=2-way bank-aliased = free). A row-major [M][K], W [K][N].
// ---------------------------------------------------------------------------
__global__ __launch_bounds__(256) void gemm128(
    const float* __restrict__ A1, const float* __restrict__ W1,
    const float* __restrict__ A2, const float* __restrict__ W2,
    const float* __restrict__ bias, const float* __restrict__ addbuf,
    float* __restrict__ Cout, int M, int N, int K, int relu)
{
    __shared__ float As[16][128];
    __shared__ float Ws[16][128];
    const int m0 = blockIdx.x * 128;
    const int n0 = blockIdx.y * 128;
    const int t  = threadIdx.x;
    const int tn = t & 15;
    const int tm = t >> 4;

    float acc[8][8] = {};

    for (int phase = 0; phase < 2; ++phase) {
        const float* A = phase ? A2 : A1;
        const float* W = phase ? W2 : W1;
        if (!A) break;
        for (int k0 = 0; k0 < K; k0 += 16) {
            // stage A: rows m0..m0+127, k k0..k0+15 -> As[k][m] (transposed)
            {
                int r  = t & 127;
                int kh = (t >> 7) * 8;
                int rg = m0 + r;
                float4 v0 = make_float4(0.f, 0.f, 0.f, 0.f), v1 = v0;
                if (rg < M) {
                    const float* p = A + (size_t)rg * K + k0 + kh;
                    v0 = *(const float4*)p;
                    v1 = *(const float4*)(p + 4);
                }
                As[kh + 0][r] = v0.x; As[kh + 1][r] = v0.y;
                As[kh + 2][r] = v0.z; As[kh + 3][r] = v0.w;
                As[kh + 4][r] = v1.x; As[kh + 5][r] = v1.y;
                As[kh + 6][r] = v1.z; As[kh + 7][r] = v1.w;
            }
            // stage W: k k0..k0+15, cols n0..n0+127 -> Ws[k][n]
            {
                int kk = t >> 4;
                int nn = (t & 15) * 4;
                const float* p = W + (size_t)(k0 + kk) * N + n0 + nn;
                *(float4*)&Ws[kk][nn]      = *(const float4*)p;
                *(float4*)&Ws[kk][nn + 64] = *(const float4*)(p + 64);
            }
            __syncthreads();
            #pragma unroll
            for (int k = 0; k < 16; ++k) {
                float4 al = *(const float4*)&As[k][tm * 4];
                float4 ah = *(const float4*)&As[k][64 + tm * 4];
                float4 wl = *(const float4*)&Ws[k][tn * 4];
                float4 wh = *(const float4*)&Ws[k][64 + tn * 4];
                float a[8] = {al.x, al.y, al.z, al.w, ah.x, ah.y, ah.z, ah.w};
                float w[8] = {wl.x, wl.y, wl.z, wl.w, wh.x, wh.y, wh.z, wh.w};
                #pragma unroll
                for (int i2 = 0; i2 < 8; ++i2) {
                    #pragma unroll
                    for (int j = 0; j < 8; ++j)
                        acc[i2][j] += a[i2] * w[j];
                }
            }
            __syncthreads();
        }
    }

    // epilogue
    float bl[8] = {};
    if (bias) {
        float4 b_lo = *(const float4*)&bias[n0 + tn * 4];
        float4 b_hi = *(const float4*)&bias[n0 + 64 + tn * 4];
        bl[0] = b_lo.x; bl[1] = b_lo.y; bl[2] = b_lo.z; bl[3] = b_lo.w;
        bl[4] = b_hi.x; bl[5] = b_hi.y; bl[6] = b_hi.z; bl[7] = b_hi.w;
    }
    #pragma unroll
    for (int i2 = 0; i2 < 8; ++i2) {
        int m = m0 + (i2 < 4 ? tm * 4 + i2 : 64 + tm * 4 + (i2 - 4));
        if (m >= M) continue;
        float4 vlo, vhi;
        vlo.x = acc[i2][0] + bl[0]; vlo.y = acc[i2][1] + bl[1];
        vlo.z = acc[i2][2] + bl[2]; vlo.w = acc[i2][3] + bl[3];
        vhi.x = acc[i2][4] + bl[4]; vhi.y = acc[i2][5] + bl[5];
        vhi.z = acc[i2][6] + bl[6]; vhi.w = acc[i2][7] + bl[7];
        if (addbuf) {
            const float* ar = addbuf + (size_t)m * N + n0;
            float4 alo = *(const float4*)&ar[tn * 4];
            float4 ahi = *(const float4*)&ar[64 + tn * 4];
            vlo.x += alo.x; vlo.y += alo.y; vlo.z += alo.z; vlo.w += alo.w;
            vhi.x += ahi.x; vhi.y += ahi.y; vhi.z += ahi.z; vhi.w += ahi.w;
        }
        if (relu) {
            vlo.x = fmaxf(vlo.x, 0.f); vlo.y = fmaxf(vlo.y, 0.f);
            vlo.z = fmaxf(vlo.z, 0.f); vlo.w = fmaxf(vlo.w, 0.f);
            vhi.x = fmaxf(vhi.x, 0.f); vhi.y = fmaxf(vhi.y, 0.f);
            vhi.z = fmaxf(vhi.z, 0.f); vhi.w = fmaxf(vhi.w, 0.f);
        }
        float* cr = Cout + (size_t)m * N + n0;
        *(float4*)&cr[tn * 4]      = vlo;
        *(float4*)&cr[64 + tn * 4] = vhi;
    }
}

// ---------------------------------------------------------------------------
// logits = hid @ Wc2 + bc2   (K=256, 2 outputs). One thread per node.
// ---------------------------------------------------------------------------
__global__ __launch_bounds__(256) void logits_kernel(
    const float* __restrict__ hid, const float* __restrict__ Wc2,
    const float* __restrict__ bc2, float* __restrict__ out, int M)
{
    __shared__ float w0[256], w1[256];
    int t = threadIdx.x;
    w0[t] = Wc2[t * 2 + 0];
    w1[t] = Wc2[t * 2 + 1];
    __syncthreads();
    int n = blockIdx.x * 256 + t;
    if (n >= M) return;
    const float* row = hid + (size_t)n * 256;
    float a0 = bc2[0], a1 = bc2[1];
    for (int k = 0; k < 256; k += 4) {
        float4 v = *(const float4*)&row[k];
        a0 += v.x * w0[k] + v.y * w0[k + 1] + v.z * w0[k + 2] + v.w * w0[k + 3];
        a1 += v.x * w1[k] + v.y * w1[k + 1] + v.z * w1[k + 2] + v.w * w1[k + 3];
    }
    out[(size_t)n * 2 + 0] = a0;
    out[(size_t)n * 2 + 1] = a1;
}

// ---------------------------------------------------------------------------
extern "C" void kernel_launch(void* const* d_in, const int* in_sizes, int n_in,
                              void* d_out, int out_size, void* d_ws, size_t ws_size,
                              hipStream_t stream)
{
    const float* x   = (const float*)d_in[0];
    const int*   ei  = (const int*)d_in[1];
    const float* Wl1 = (const float*)d_in[2];
    const float* Wr1 = (const float*)d_in[3];
    const float* b1  = (const float*)d_in[4];
    const float* Wl2 = (const float*)d_in[5];
    const float* Wr2 = (const float*)d_in[6];
    const float* b2  = (const float*)d_in[7];
    const float* Wc1 = (const float*)d_in[8];
    const float* bc1 = (const float*)d_in[9];
    const float* Wc2 = (const float*)d_in[10];
    const float* bc2 = (const float*)d_in[11];

    const int N = in_sizes[0] / 128;   // 100000
    const int E = in_sizes[1] / 2;     // 1600000

    char* ws = (char*)d_ws;
    size_t off = 0;
    auto alloc = [&](size_t bytes) -> void* {
        void* p = ws + off;
        off += (bytes + 255) & ~(size_t)255;
        return p;
    };
    int*   deg   = (int*)  alloc((size_t)N * 4);
    int*   col   = (int*)  alloc((size_t)N * MAXDEG * 4);
    float* meanb = (float*)alloc((size_t)N * 256 * 4);  // agg1 / t2 (lo half) + aggt (hi half)
    float* h1    = (float*)alloc((size_t)N * 256 * 4);  // h1, later hid

    float* agg1  = meanb;                    // [N][128]
    float* t2    = meanb;                    // [N][128] (agg1 dead by then)
    float* aggt  = meanb + (size_t)N * 128;  // [N][128]
    float* hid   = h1;                       // [N][256] (h1 dead by then)

    float* h2     = (float*)d_out;                       // [N][128]  (output 0)
    float* logits = (float*)d_out + (size_t)N * 128;     // [N][2]    (output 1)

    const int gm = (N + 127) / 128;

    hipMemsetAsync(deg, 0, (size_t)N * 4, stream);
    build_buckets<<<dim3((E + 255) / 256), dim3(256), 0, stream>>>(ei, ei + E, deg, col, E);

    // Layer 1: h1 = relu(mean(x) @ Wl1 + x @ Wr1 + b1)   [N][256]
    agg_mean2<128><<<dim3((N + 3) / 4), dim3(256), 0, stream>>>(x, col, deg, agg1, N);
    gemm128<<<dim3(gm, 2), dim3(256), 0, stream>>>(
        agg1, Wl1, x, Wr1, b1, nullptr, h1, N, 256, 128, 1);

    // Layer 2 (aggregate-after-transform): t2 = h1 @ Wl2; h2 = mean(t2) + h1 @ Wr2 + b2
    gemm128<<<dim3(gm, 1), dim3(256), 0, stream>>>(
        h1, Wl2, nullptr, nullptr, nullptr, nullptr, t2, N, 128, 256, 0);
    agg_mean2<128><<<dim3((N + 3) / 4), dim3(256), 0, stream>>>(t2, col, deg, aggt, N);
    gemm128<<<dim3(gm, 1), dim3(256), 0, stream>>>(
        h1, Wr2, nullptr, nullptr, b2, aggt, h2, N, 128, 256, 0);

    // Classifier: hid = relu(h2 @ Wc1 + bc1) [N][256], then logits
    gemm128<<<dim3(gm, 2), dim3(256), 0, stream>>>(
        h2, Wc1, nullptr, nullptr, bc1, nullptr, hid, N, 256, 128, 1);
    logits_kernel<<<dim3((N + 255) / 256), dim3(256), 0, stream>>>(
        hid, Wc2, bc2, logits, N);
}

// Round 3
// 800.648 us; speedup vs baseline: 1.4625x; 1.0505x over previous
//
#include <hip/hip_runtime.h>

#define MAXDEG 96

typedef __bf16 bf16x8 __attribute__((ext_vector_type(8)));
typedef float f32x4 __attribute__((ext_vector_type(4)));

__device__ inline ushort f2bf(float f) {
    unsigned u = __builtin_bit_cast(unsigned, f);
    return (ushort)((u + 0x7fffu + ((u >> 16) & 1u)) >> 16);
}
__device__ inline float bf2f(ushort h) {
    unsigned u = ((unsigned)h) << 16;
    return __builtin_bit_cast(float, u);
}

// ---------------------------------------------------------------------------
// Adjacency buckets
// ---------------------------------------------------------------------------
__global__ __launch_bounds__(256) void build_buckets(
    const int* __restrict__ src, const int* __restrict__ dst,
    int* __restrict__ deg, int* __restrict__ col, int E)
{
    int e = blockIdx.x * 256 + threadIdx.x;
    if (e >= E) return;
    int d = dst[e];
    int slot = atomicAdd(&deg[d], 1);
    if (slot < MAXDEG) col[(size_t)d * MAXDEG + slot] = src[e];
}

// ---------------------------------------------------------------------------
// Elementwise f32 -> (hi,lo) bf16 split. i covers n/4 float4s.
// ---------------------------------------------------------------------------
__global__ __launch_bounds__(256) void fsplit(
    const float* __restrict__ X, ushort* __restrict__ Hi, ushort* __restrict__ Lo, int n4)
{
    int i = blockIdx.x * 256 + threadIdx.x;
    if (i >= n4) return;
    float4 v = *(const float4*)(X + (size_t)i * 4);
    ushort h0 = f2bf(v.x), h1 = f2bf(v.y), h2 = f2bf(v.z), h3 = f2bf(v.w);
    ushort l0 = f2bf(v.x - bf2f(h0)), l1 = f2bf(v.y - bf2f(h1));
    ushort l2 = f2bf(v.z - bf2f(h2)), l3 = f2bf(v.w - bf2f(h3));
    *(ushort4*)(Hi + (size_t)i * 4) = make_ushort4(h0, h1, h2, h3);
    *(ushort4*)(Lo + (size_t)i * 4) = make_ushort4(l0, l1, l2, l3);
}

// ---------------------------------------------------------------------------
// Weight transpose+split: Wt[n][k] = split(W[k][n]).  Tiny matrices.
// ---------------------------------------------------------------------------
__global__ __launch_bounds__(256) void wsplit(
    const float* __restrict__ W, ushort* __restrict__ Thi, ushort* __restrict__ Tlo,
    int K, int N)
{
    int idx = blockIdx.x * 256 + threadIdx.x;
    if (idx >= K * N) return;
    int n = idx / K, k = idx % K;
    float v = W[(size_t)k * N + n];
    ushort h = f2bf(v);
    Thi[idx] = h;
    Tlo[idx] = f2bf(v - bf2f(h));
}

// ---------------------------------------------------------------------------
// Mean-aggregate (C=128), f32 in, f32 out. One wave per node, 2 floats/lane.
// ---------------------------------------------------------------------------
__global__ __launch_bounds__(256) void agg_mean_f32(
    const float* __restrict__ X, const int* __restrict__ col,
    const int* __restrict__ deg, float* __restrict__ out, int N)
{
    int gw = (blockIdx.x * 256 + threadIdx.x) >> 6;
    if (gw >= N) return;
    int lane = threadIdx.x & 63;
    int d = deg[gw];
    int dc = d < MAXDEG ? d : MAXDEG;
    const int* cl = col + (size_t)gw * MAXDEG;
    float a0 = 0.f, a1 = 0.f;
    int i = 0;
    for (; i + 4 <= dc; i += 4) {
        int4 id4 = *(const int4*)(cl + i);
        float2 v0 = *(const float2*)(X + (size_t)id4.x * 128 + lane * 2);
        float2 v1 = *(const float2*)(X + (size_t)id4.y * 128 + lane * 2);
        float2 v2 = *(const float2*)(X + (size_t)id4.z * 128 + lane * 2);
        float2 v3 = *(const float2*)(X + (size_t)id4.w * 128 + lane * 2);
        a0 += (v0.x + v1.x) + (v2.x + v3.x);
        a1 += (v0.y + v1.y) + (v2.y + v3.y);
    }
    for (; i < dc; ++i) {
        float2 v = *(const float2*)(X + (size_t)cl[i] * 128 + lane * 2);
        a0 += v.x; a1 += v.y;
    }
    float inv = 1.0f / (float)(d > 1 ? d : 1);
    *(float2*)(out + (size_t)gw * 128 + lane * 2) = make_float2(a0 * inv, a1 * inv);
}

// ---------------------------------------------------------------------------
// Mean-aggregate (C=128), f32 in, SPLIT bf16 out.
// ---------------------------------------------------------------------------
__global__ __launch_bounds__(256) void agg_mean_split(
    const float* __restrict__ X, const int* __restrict__ col,
    const int* __restrict__ deg, ushort* __restrict__ Ohi, ushort* __restrict__ Olo, int N)
{
    int gw = (blockIdx.x * 256 + threadIdx.x) >> 6;
    if (gw >= N) return;
    int lane = threadIdx.x & 63;
    int d = deg[gw];
    int dc = d < MAXDEG ? d : MAXDEG;
    const int* cl = col + (size_t)gw * MAXDEG;
    float a0 = 0.f, a1 = 0.f;
    int i = 0;
    for (; i + 4 <= dc; i += 4) {
        int4 id4 = *(const int4*)(cl + i);
        float2 v0 = *(const float2*)(X + (size_t)id4.x * 128 + lane * 2);
        float2 v1 = *(const float2*)(X + (size_t)id4.y * 128 + lane * 2);
        float2 v2 = *(const float2*)(X + (size_t)id4.z * 128 + lane * 2);
        float2 v3 = *(const float2*)(X + (size_t)id4.w * 128 + lane * 2);
        a0 += (v0.x + v1.x) + (v2.x + v3.x);
        a1 += (v0.y + v1.y) + (v2.y + v3.y);
    }
    for (; i < dc; ++i) {
        float2 v = *(const float2*)(X + (size_t)cl[i] * 128 + lane * 2);
        a0 += v.x; a1 += v.y;
    }
    float inv = 1.0f / (float)(d > 1 ? d : 1);
    float m0 = a0 * inv, m1 = a1 * inv;
    ushort h0 = f2bf(m0), h1 = f2bf(m1);
    *(ushort2*)(Ohi + (size_t)gw * 128 + lane * 2) = make_ushort2(h0, h1);
    *(ushort2*)(Olo + (size_t)gw * 128 + lane * 2) =
        make_ushort2(f2bf(m0 - bf2f(h0)), f2bf(m1 - bf2f(h1)));
}

// ---------------------------------------------------------------------------
// Split-bf16 MFMA GEMM.  C = act( sum_ph A_ph @ B_ph  [+ addbuf] [+ bias] )
// where each A@B is computed as Ahi@Bhi + Alo@Bhi + Ahi@Blo (3 bf16 passes).
// A row-major [M][K] bf16 (hi/lo pair); B pre-transposed [N][K] bf16 pair.
// 128x128 tile, BK=32, 4 waves (2x2 of 64x64), mfma_f32_16x16x32_bf16.
// LDS tiles [128 rows][32 k] bf16 with 16B-slot XOR swizzle (slot ^= r&3):
// stage-writes conflict-free, frag-reads 2-way (free).
// ---------------------------------------------------------------------------
__global__ __launch_bounds__(256) void gemm_mfma(
    const ushort* __restrict__ A1hi, const ushort* __restrict__ A1lo,
    const ushort* __restrict__ B1hi, const ushort* __restrict__ B1lo,
    const ushort* __restrict__ A2hi, const ushort* __restrict__ A2lo,
    const ushort* __restrict__ B2hi, const ushort* __restrict__ B2lo,
    const float* __restrict__ bias, const float* __restrict__ addbuf,
    float* __restrict__ outf, ushort* __restrict__ outhi, ushort* __restrict__ outlo,
    int M, int N, int K, int relu)
{
    __shared__ __align__(16) ushort As[4096];
    __shared__ __align__(16) ushort Bs[4096];
    const int t  = threadIdx.x;
    const int m0 = blockIdx.x * 128;
    const int n0 = blockIdx.y * 128;
    const int l  = t & 63;
    const int wv = t >> 6;
    const int wr = (wv >> 1) * 64;
    const int wc = (wv & 1) * 64;
    const int lr = l & 15;
    const int kb = l >> 4;

    f32x4 acc[4][4] = {};

    const int nph = A2hi ? 2 : 1;
    for (int ph = 0; ph < nph; ++ph) {
        const ushort* Ah = ph ? A2hi : A1hi;
        const ushort* Al = ph ? A2lo : A1lo;
        const ushort* Bh = ph ? B2hi : B1hi;
        const ushort* Bl = ph ? B2lo : B1lo;
        for (int seg = 0; seg < 3; ++seg) {
            const ushort* Aseg = (seg == 1) ? Al : Ah;
            const ushort* Bseg = (seg == 2) ? Bl : Bh;
            for (int k0 = 0; k0 < K; k0 += 32) {
                #pragma unroll
                for (int h = 0; h < 2; ++h) {
                    int q  = h * 256 + t;
                    int r  = q >> 2;
                    int kq = q & 3;
                    int ks = kq ^ (r & 3);
                    uint4 av = make_uint4(0, 0, 0, 0);
                    if (m0 + r < M)
                        av = *(const uint4*)(Aseg + (size_t)(m0 + r) * K + k0 + kq * 8);
                    *(uint4*)&As[r * 32 + ks * 8] = av;
                    uint4 bv = *(const uint4*)(Bseg + (size_t)(n0 + r) * K + k0 + kq * 8);
                    *(uint4*)&Bs[r * 32 + ks * 8] = bv;
                }
                __syncthreads();
                bf16x8 af[4], bf[4];
                #pragma unroll
                for (int mi = 0; mi < 4; ++mi) {
                    int r = wr + mi * 16 + lr;
                    af[mi] = *(const bf16x8*)&As[r * 32 + ((kb ^ (r & 3)) * 8)];
                }
                #pragma unroll
                for (int nj = 0; nj < 4; ++nj) {
                    int c = wc + nj * 16 + lr;
                    bf[nj] = *(const bf16x8*)&Bs[c * 32 + ((kb ^ (c & 3)) * 8)];
                }
                #pragma unroll
                for (int mi = 0; mi < 4; ++mi)
                    #pragma unroll
                    for (int nj = 0; nj < 4; ++nj)
                        acc[mi][nj] = __builtin_amdgcn_mfma_f32_16x16x32_bf16(
                            af[mi], bf[nj], acc[mi][nj], 0, 0, 0);
                __syncthreads();
            }
        }
    }

    // epilogue: D lane map col = l&15, row = (l>>4)*4 + reg
    const int rbase = (l >> 4) * 4;
    #pragma unroll
    for (int nj = 0; nj < 4; ++nj) {
        int colg = n0 + wc + nj * 16 + lr;
        float bv = bias ? bias[colg] : 0.f;
        #pragma unroll
        for (int mi = 0; mi < 4; ++mi) {
            #pragma unroll
            for (int reg = 0; reg < 4; ++reg) {
                int rowg = m0 + wr + mi * 16 + rbase + reg;
                if (rowg >= M) continue;
                float v = acc[mi][nj][reg] + bv;
                if (addbuf) v += addbuf[(size_t)rowg * N + colg];
                if (relu) v = fmaxf(v, 0.f);
                if (outf) outf[(size_t)rowg * N + colg] = v;
                if (outhi) {
                    ushort hv = f2bf(v);
                    outhi[(size_t)rowg * N + colg] = hv;
                    outlo[(size_t)rowg * N + colg] = f2bf(v - bf2f(hv));
                }
            }
        }
    }
}

// ---------------------------------------------------------------------------
// logits = hid @ Wc2 + bc2   (K=256, 2 outputs).
// ---------------------------------------------------------------------------
__global__ __launch_bounds__(256) void logits_kernel(
    const float* __restrict__ hid, const float* __restrict__ Wc2,
    const float* __restrict__ bc2, float* __restrict__ out, int M)
{
    __shared__ float w0[256], w1[256];
    int t = threadIdx.x;
    w0[t] = Wc2[t * 2 + 0];
    w1[t] = Wc2[t * 2 + 1];
    __syncthreads();
    int n = blockIdx.x * 256 + t;
    if (n >= M) return;
    const float* row = hid + (size_t)n * 256;
    float a0 = bc2[0], a1 = bc2[1];
    for (int k = 0; k < 256; k += 4) {
        float4 v = *(const float4*)&row[k];
        a0 += v.x * w0[k] + v.y * w0[k + 1] + v.z * w0[k + 2] + v.w * w0[k + 3];
        a1 += v.x * w1[k] + v.y * w1[k + 1] + v.z * w1[k + 2] + v.w * w1[k + 3];
    }
    out[(size_t)n * 2 + 0] = a0;
    out[(size_t)n * 2 + 1] = a1;
}

// ---------------------------------------------------------------------------
extern "C" void kernel_launch(void* const* d_in, const int* in_sizes, int n_in,
                              void* d_out, int out_size, void* d_ws, size_t ws_size,
                              hipStream_t stream)
{
    const float* x   = (const float*)d_in[0];
    const int*   ei  = (const int*)d_in[1];
    const float* Wl1 = (const float*)d_in[2];
    const float* Wr1 = (const float*)d_in[3];
    const float* b1  = (const float*)d_in[4];
    const float* Wl2 = (const float*)d_in[5];
    const float* Wr2 = (const float*)d_in[6];
    const float* b2  = (const float*)d_in[7];
    const float* Wc1 = (const float*)d_in[8];
    const float* bc1 = (const float*)d_in[9];
    const float* Wc2 = (const float*)d_in[10];
    const float* bc2 = (const float*)d_in[11];

    const int N = in_sizes[0] / 128;   // 100000
    const int E = in_sizes[1] / 2;     // 1600000

    char* ws = (char*)d_ws;
    size_t off = 0;
    auto alloc = [&](size_t bytes) -> void* {
        void* p = ws + off;
        off += (bytes + 255) & ~(size_t)255;
        return p;
    };
    const size_t NE128 = (size_t)N * 128;   // 12.8M elems
    const size_t NE256 = (size_t)N * 256;

    int*    deg   = (int*)alloc((size_t)N * 4);
    int*    col   = (int*)alloc((size_t)N * MAXDEG * 4);
    char*   slabA = (char*)alloc(NE128 * 4);   // xs pair -> t2 f32 -> h2s pair
    char*   slabB = (char*)alloc(NE128 * 4);   // a1 pair -> aggt f32
    char*   slabC = (char*)alloc(NE256 * 4);   // h1 pair -> hid f32
    ushort* wl1h = (ushort*)alloc(128 * 256 * 2); ushort* wl1l = (ushort*)alloc(128 * 256 * 2);
    ushort* wr1h = (ushort*)alloc(128 * 256 * 2); ushort* wr1l = (ushort*)alloc(128 * 256 * 2);
    ushort* wl2h = (ushort*)alloc(256 * 128 * 2); ushort* wl2l = (ushort*)alloc(256 * 128 * 2);
    ushort* wr2h = (ushort*)alloc(256 * 128 * 2); ushort* wr2l = (ushort*)alloc(256 * 128 * 2);
    ushort* wc1h = (ushort*)alloc(128 * 256 * 2); ushort* wc1l = (ushort*)alloc(128 * 256 * 2);

    ushort* xs_hi = (ushort*)slabA;           ushort* xs_lo = (ushort*)slabA + NE128;
    float*  t2    = (float*)slabA;
    ushort* h2s_hi = (ushort*)slabA;          ushort* h2s_lo = (ushort*)slabA + NE128;
    ushort* a1_hi = (ushort*)slabB;           ushort* a1_lo = (ushort*)slabB + NE128;
    float*  aggt  = (float*)slabB;
    ushort* h1_hi = (ushort*)slabC;           ushort* h1_lo = (ushort*)slabC + NE256;
    float*  hid   = (float*)slabC;

    float* h2     = (float*)d_out;                   // [N][128]  (output 0)
    float* logits = (float*)d_out + NE128;           // [N][2]    (output 1)

    const int gm = (N + 127) / 128;

    hipMemsetAsync(deg, 0, (size_t)N * 4, stream);
    build_buckets<<<dim3((E + 255) / 256), dim3(256), 0, stream>>>(ei, ei + E, deg, col, E);

    // splits
    fsplit<<<dim3((int)(NE128 / 4 + 255) / 256), dim3(256), 0, stream>>>(x, xs_hi, xs_lo, (int)(NE128 / 4));
    wsplit<<<dim3(128), dim3(256), 0, stream>>>(Wl1, wl1h, wl1l, 128, 256);
    wsplit<<<dim3(128), dim3(256), 0, stream>>>(Wr1, wr1h, wr1l, 128, 256);
    wsplit<<<dim3(128), dim3(256), 0, stream>>>(Wl2, wl2h, wl2l, 256, 128);
    wsplit<<<dim3(128), dim3(256), 0, stream>>>(Wr2, wr2h, wr2l, 256, 128);
    wsplit<<<dim3(128), dim3(256), 0, stream>>>(Wc1, wc1h, wc1l, 128, 256);

    // Layer 1: h1 = relu(mean(x)@Wl1 + x@Wr1 + b1)  -> split pair [N][256]
    agg_mean_split<<<dim3((N + 3) / 4), dim3(256), 0, stream>>>(x, col, deg, a1_hi, a1_lo, N);
    gemm_mfma<<<dim3(gm, 2), dim3(256), 0, stream>>>(
        a1_hi, a1_lo, wl1h, wl1l, xs_hi, xs_lo, wr1h, wr1l,
        b1, nullptr, nullptr, h1_hi, h1_lo, N, 256, 128, 1);

    // Layer 2 (aggregate-after-transform): t2 = h1@Wl2 (f32);
    gemm_mfma<<<dim3(gm, 1), dim3(256), 0, stream>>>(
        h1_hi, h1_lo, wl2h, wl2l, nullptr, nullptr, nullptr, nullptr,
        nullptr, nullptr, t2, nullptr, nullptr, N, 128, 256, 0);
    agg_mean_f32<<<dim3((N + 3) / 4), dim3(256), 0, stream>>>(t2, col, deg, aggt, N);
    // h2 = h1@Wr2 + aggt + b2 -> d_out f32 AND split pair for classifier
    gemm_mfma<<<dim3(gm, 1), dim3(256), 0, stream>>>(
        h1_hi, h1_lo, wr2h, wr2l, nullptr, nullptr, nullptr, nullptr,
        b2, aggt, h2, h2s_hi, h2s_lo, N, 128, 256, 0);

    // Classifier: hid = relu(h2@Wc1 + bc1) -> f32 [N][256], then logits
    gemm_mfma<<<dim3(gm, 2), dim3(256), 0, stream>>>(
        h2s_hi, h2s_lo, wc1h, wc1l, nullptr, nullptr, nullptr, nullptr,
        bc1, nullptr, hid, nullptr, nullptr, N, 256, 128, 1);
    logits_kernel<<<dim3((N + 255) / 256), dim3(256), 0, stream>>>(
        hid, Wc2, bc2, logits, N);
}